// Round 15
// baseline (146.163 us; speedup 1.0000x reference)
//
#include <hip/hip_runtime.h>
#include <cstdint>
#include <cstddef>

#define T_SEQ 2048
#define D_EMB 1024
#define H_HEADS 16
#define MROWS 4096
// scale * log2(e): softmax computed in exp2 domain; folded into q projection
#define SC2 (0.03125f * 1.44269504f)
#define MASKNEG (-1e30f)

typedef __attribute__((ext_vector_type(8))) short bf16x8;
typedef __attribute__((ext_vector_type(4))) float f32x4;
typedef __attribute__((ext_vector_type(16))) float f32x16;
typedef __attribute__((ext_vector_type(4))) unsigned short us4;

__device__ __forceinline__ unsigned short f2bf(float f) {
  union { float f; uint32_t u; } v; v.f = f;
  uint32_t u = v.u;
  return (unsigned short)((u + 0x7FFFu + ((u >> 16) & 1u)) >> 16);
}

__device__ __forceinline__ uint32_t cvtpk(float lo, float hi) {
  uint32_t r;
  asm("v_cvt_pk_bf16_f32 %0, %1, %2" : "=v"(r) : "v"(lo), "v"(hi));
  return r;
}

__device__ __forceinline__ float fexp2(float x) {
  float r;
  asm("v_exp_f32 %0, %1" : "=v"(r) : "v"(x));
  return r;
}

__device__ __forceinline__ float bf2f(unsigned short u) {
  union { uint32_t u; float f; } v; v.u = ((uint32_t)u) << 16;
  return v.f;
}

__device__ __forceinline__ void gl16(const void* g, void* l) {
  __builtin_amdgcn_global_load_lds(
      (const __attribute__((address_space(1))) unsigned int*)g,
      (__attribute__((address_space(3))) unsigned int*)l, 16, 0, 0);
}

// ---------------- fused fp32 -> bf16 (3 inputs + 4 weights, one dispatch) ----------------
__global__ __launch_bounds__(256) void cvt_all(
    const float* __restrict__ Q, const float* __restrict__ K, const float* __restrict__ V,
    const float* __restrict__ Wq, const float* __restrict__ Wk,
    const float* __restrict__ Wv, const float* __restrict__ Wo,
    unsigned short* __restrict__ Qb, unsigned short* __restrict__ Kb,
    unsigned short* __restrict__ Vb,
    unsigned short* __restrict__ Wqb, unsigned short* __restrict__ Wkb,
    unsigned short* __restrict__ Wvb, unsigned short* __restrict__ Wob) {
  int i = blockIdx.x * 256 + threadIdx.x;
  const float* src;
  unsigned short* dst;
  int j;
  if (i < 3145728) {
    int s = i >> 20;
    j = i & 1048575;
    src = (s == 0) ? Q : (s == 1) ? K : V;
    dst = (s == 0) ? Qb : (s == 1) ? Kb : Vb;
  } else {
    int k = i - 3145728;
    int s = k >> 18;
    j = k & 262143;
    src = (s == 0) ? Wq : (s == 1) ? Wk : (s == 2) ? Wv : Wo;
    dst = (s == 0) ? Wqb : (s == 1) ? Wkb : (s == 2) ? Wvb : Wob;
  }
  float4 f = ((const float4*)src)[j];
  us4 o;
  o[0] = f2bf(f.x); o[1] = f2bf(f.y); o[2] = f2bf(f.z); o[3] = f2bf(f.w);
  ((us4*)dst)[j] = o;
}

// ---------------- fused QKV projection GEMM (BM=128 BN=64, 6 blocks/CU) ----------------
__global__ __launch_bounds__(256) void qkv_gemm(
    const unsigned short* __restrict__ Qb, const unsigned short* __restrict__ Kb,
    const unsigned short* __restrict__ Vb,
    const unsigned short* __restrict__ Wqb, const unsigned short* __restrict__ Wkb,
    const unsigned short* __restrict__ Wvb,
    const float* __restrict__ bq, const float* __restrict__ bk, const float* __restrict__ bv,
    unsigned short* __restrict__ qo, unsigned short* __restrict__ ko,
    unsigned short* __restrict__ vto) {
  const int swz = (blockIdx.x & 7) * 192 + (blockIdx.x >> 3);
  const int bx = swz & 15, by = (swz >> 4) & 31, z = swz >> 9;
  const unsigned short* A = (z == 0) ? Qb : (z == 1) ? Kb : Vb;
  const unsigned short* W = (z == 0) ? Wqb : (z == 1) ? Wkb : Wvb;
  const float* bias = (z == 0) ? bq : (z == 1) ? bk : bv;

  __shared__ __align__(16) unsigned short Asm[2][128 * 32];
  __shared__ __align__(16) unsigned short Bsm[2][64 * 32];

  const int tid = threadIdx.x;
  const int lane = tid & 63, w = tid >> 6;
  const int fq = lane >> 4, fr = lane & 15;
  const int brow = by * 128, bcol = bx * 64;
  const int wr = w * 32;

  f32x4 acc[2][4] = {};

#define QKV_STAGE(buf, k0)                                                     \
  {                                                                            \
    _Pragma("unroll") for (int it = 0; it < 2; ++it) {                         \
      int idx = it * 256 + tid;                                                \
      int row = idx >> 2, ce = (idx & 3) * 8;                                  \
      gl16(&A[(size_t)(brow + row) * D_EMB + (k0) + ce],                       \
           (char*)Asm[buf] + idx * 16);                                        \
    }                                                                          \
    {                                                                          \
      int row = tid >> 2, ce = (tid & 3) * 8;                                  \
      gl16(&W[(size_t)(bcol + row) * D_EMB + (k0) + ce],                       \
           (char*)Bsm[buf] + tid * 16);                                        \
    }                                                                          \
  }

#define QKV_COMPUTE(buf)                                                       \
  {                                                                            \
    bf16x8 af[2], bfr[4];                                                      \
    _Pragma("unroll") for (int i = 0; i < 2; ++i)                              \
        af[i] = *(const bf16x8*)((const char*)Asm[buf] +                       \
                                 (wr + i * 16 + fr) * 64 + fq * 16);           \
    _Pragma("unroll") for (int j = 0; j < 4; ++j)                              \
        bfr[j] = *(const bf16x8*)((const char*)Bsm[buf] +                      \
                                  (j * 16 + fr) * 64 + fq * 16);               \
    _Pragma("unroll") for (int i = 0; i < 2; ++i)                              \
        _Pragma("unroll") for (int j = 0; j < 4; ++j)                          \
            acc[i][j] = __builtin_amdgcn_mfma_f32_16x16x32_bf16(               \
                af[i], bfr[j], acc[i][j], 0, 0, 0);                            \
  }

  QKV_STAGE(0, 0);
  __syncthreads();
#pragma unroll 1
  for (int t = 0; t < 32; t += 2) {
    QKV_STAGE(1, (t + 1) * 32);
    QKV_COMPUTE(0);
    __syncthreads();
    if (t + 2 < 32) QKV_STAGE(0, (t + 2) * 32);
    QKV_COMPUTE(1);
    __syncthreads();
  }

  // epilogue
#pragma unroll
  for (int i = 0; i < 2; ++i) {
#pragma unroll
    for (int j = 0; j < 4; ++j) {
      int r0 = brow + wr + i * 16 + fq * 4;
      int cc = bcol + j * 16 + fr;
      float bb = bias[cc];
      if (z < 2) {
        unsigned short* O = (z == 0) ? qo : ko;
        float sc = (z == 0) ? SC2 : 1.0f;
#pragma unroll
        for (int q = 0; q < 4; ++q)
          O[(size_t)(r0 + q) * D_EMB + cc] = f2bf((acc[i][j][q] + bb) * sc);
      } else {
        int hh = cc >> 6, dd = cc & 63;
        int mm = r0 >> 11, tt = r0 & 2047;
        us4 pk;
#pragma unroll
        for (int q = 0; q < 4; ++q) pk[q] = f2bf(acc[i][j][q] + bb);
        *(us4*)&vto[((size_t)((mm * H_HEADS + hh) * 64 + dd)) * T_SEQ + tt] = pk;
      }
    }
  }
}

// ---------------- output projection GEMM ----------------
__global__ __launch_bounds__(256) void out_gemm(const unsigned short* __restrict__ Ab,
                                                const unsigned short* __restrict__ Wb,
                                                const float* __restrict__ bias,
                                                float* __restrict__ Out) {
  const int swz = (blockIdx.x & 7) * 64 + (blockIdx.x >> 3);
  const int bx = swz & 15, by = swz >> 4;

  __shared__ __align__(16) unsigned short Asm[2][128 * 32];
  __shared__ __align__(16) unsigned short Bsm[2][64 * 32];
  const int tid = threadIdx.x;
  const int lane = tid & 63, w = tid >> 6;
  const int fq = lane >> 4, fr = lane & 15;
  const int brow = by * 128, bcol = bx * 64;
  const int wr = w * 32;

  f32x4 acc[2][4] = {};

#define OUT_STAGE(buf, k0)                                                     \
  {                                                                            \
    _Pragma("unroll") for (int it = 0; it < 2; ++it) {                         \
      int idx = it * 256 + tid;                                                \
      int row = idx >> 2, ce = (idx & 3) * 8;                                  \
      gl16(&Ab[(size_t)(brow + row) * D_EMB + (k0) + ce],                      \
           (char*)Asm[buf] + idx * 16);                                        \
    }                                                                          \
    {                                                                          \
      int row = tid >> 2, ce = (tid & 3) * 8;                                  \
      gl16(&Wb[(size_t)(bcol + row) * D_EMB + (k0) + ce],                      \
           (char*)Bsm[buf] + tid * 16);                                        \
    }                                                                          \
  }

#define OUT_COMPUTE(buf)                                                       \
  {                                                                            \
    bf16x8 af[2], bfr[4];                                                      \
    _Pragma("unroll") for (int i = 0; i < 2; ++i)                              \
        af[i] = *(const bf16x8*)((const char*)Asm[buf] +                       \
                                 (wr + i * 16 + fr) * 64 + fq * 16);           \
    _Pragma("unroll") for (int j = 0; j < 4; ++j)                              \
        bfr[j] = *(const bf16x8*)((const char*)Bsm[buf] +                      \
                                  (j * 16 + fr) * 64 + fq * 16);               \
    _Pragma("unroll") for (int i = 0; i < 2; ++i)                              \
        _Pragma("unroll") for (int j = 0; j < 4; ++j)                          \
            acc[i][j] = __builtin_amdgcn_mfma_f32_16x16x32_bf16(               \
                af[i], bfr[j], acc[i][j], 0, 0, 0);                            \
  }

  OUT_STAGE(0, 0);
  __syncthreads();
#pragma unroll 1
  for (int t = 0; t < 32; t += 2) {
    OUT_STAGE(1, (t + 1) * 32);
    OUT_COMPUTE(0);
    __syncthreads();
    if (t + 2 < 32) OUT_STAGE(0, (t + 2) * 32);
    OUT_COMPUTE(1);
    __syncthreads();
  }

#pragma unroll
  for (int i = 0; i < 2; ++i)
#pragma unroll
    for (int j = 0; j < 4; ++j) {
      int r0 = brow + wr + i * 16 + fq * 4;
      int cc = bcol + j * 16 + fr;
      float bb = bias[cc];
#pragma unroll
      for (int q = 0; q < 4; ++q)
        Out[(size_t)(r0 + q) * D_EMB + cc] = acc[i][j][q] + bb;
    }
}

// ---------------- Flash attention (grid K-split, KVBLK=64, 32x32 MFMA) ----------------
// grid = 512*nsp blocks XCD-swizzled; block = 256 thr (4 waves x 32 q). sp selects
// a (32/nsp)-tile slice of the 32 key-tiles of 64. LDS 17KB -> up to 8 blocks/CU
// (32 waves/CU at VGPR<=64) when nsp=4 (grid 2048). Scalar li + launch_bounds
// (256,4). Partial O (bf16) + li (f32) out; combine merges nsp partials.
// NOTE: lipart must NOT alias q_b/k_b/vt_b (attn reads them concurrently) -- R14
// aliased k_b and raced to NaN; it now lives in dead Wq_b space (ws+0).
__global__ __launch_bounds__(256, 4) void attn_fwd(const unsigned short* __restrict__ qb,
                                                   const unsigned short* __restrict__ kb,
                                                   const unsigned short* __restrict__ vtb,
                                                   const int* __restrict__ maskg,
                                                   unsigned short* __restrict__ opart,
                                                   float* __restrict__ lipart,
                                                   int nsp) {
  const int cpx = gridDim.x >> 3;
  const int swzb = (blockIdx.x & 7) * cpx + (blockIdx.x >> 3);
  const int qt = swzb & 15, h = (swzb >> 4) & 15, mI = (swzb >> 8) & 1, sp = swzb >> 9;
  const int ntpb = 32 / nsp;                      // key-tiles (of 64) per block
  const int tid = threadIdx.x;
  const int lane = tid & 63, w = tid >> 6;
  const int lq = lane & 31, h2 = lane >> 5;
  const int xk = (lq & 7) << 4;
  const int vx = (lq & 7) << 4;

  __shared__ __align__(16) unsigned short Ksm[64 * 64];   // [key][d], swizzled
  __shared__ __align__(16) unsigned short Vsm[64 * 64];   // [d][key], swizzled
  __shared__ __align__(16) float Msm[64];
  __shared__ int moks[32];

  char* KsmB = (char*)Ksm;
  char* VsmB = (char*)Vsm;

  // ---- per-(m,tile-of-64) all-ones mask flags (once per block) ----
  if (tid < 32) moks[tid] = 1;
  __syncthreads();
  {
    int bad = 0;
    const int4* mg = (const int4*)&maskg[mI * T_SEQ + tid * 8];
    int4 a = mg[0], b = mg[1];
    bad |= (a.x == 0) | (a.y == 0) | (a.z == 0) | (a.w == 0);
    bad |= (b.x == 0) | (b.y == 0) | (b.z == 0) | (b.w == 0);
    if (bad) moks[tid >> 3] = 0;
  }
  __syncthreads();
  uint32_t okbits = 0;
#pragma unroll
  for (int i = 0; i < 32; ++i) okbits |= (uint32_t)(moks[i] != 0) << i;

  // ---- Q fragments in registers (B-frag: col=q=lq, k=d) ----
  const int qrow = qt * 128 + w * 32 + lq;
  bf16x8 qf[4];
#pragma unroll
  for (int db = 0; db < 4; ++db)
    qf[db] = *(const bf16x8*)&qb[((size_t)(mI * T_SEQ) + qrow) * D_EMB + h * 64 + db * 16 + h2 * 8];

  f32x16 oacc[2] = {};
  float li = 0.f;

  const unsigned short* kpan = kb + (size_t)(mI * T_SEQ) * D_EMB + h * 64;
  const unsigned short* vpan = vtb + (size_t)(mI * H_HEADS + h) * 64 * T_SEQ;

#pragma unroll 1
  for (int t = sp * ntpb; t < sp * ntpb + ntpb; ++t) {
    const int okv = (okbits >> t) & 1;
    const int k0s = t * 64;
    // ---- stage K [64][64] + Vt [64][64] (single buffer, 17KB) ----
#pragma unroll
    for (int it = 0; it < 2; ++it) {
      int idx = it * 256 + tid;
      int row = idx >> 3;
      int sb = ((idx & 7) * 16) ^ ((row & 7) << 4);
      gl16(kpan + (size_t)(k0s + row) * D_EMB + (sb >> 1), KsmB + idx * 16);
    }
#pragma unroll
    for (int it = 0; it < 2; ++it) {
      int idx = it * 256 + tid;
      int row = idx >> 3;
      int sb = ((idx & 7) * 16) ^ ((row & 7) << 4);
      gl16(vpan + (size_t)row * T_SEQ + k0s + (sb >> 1), VsmB + idx * 16);
    }
    if (!okv && tid < 64)
      Msm[tid] = (maskg[mI * T_SEQ + k0s + tid] == 0) ? MASKNEG : 0.f;
    __syncthreads();

    // ---- 2 key-blocks of 32 ----
#pragma unroll 1
    for (int kbk = 0; kbk < 2; ++kbk) {
      f32x16 sv = {};
      const char* kr = KsmB + (kbk * 32 + lq) * 128;
#pragma unroll
      for (int db = 0; db < 4; ++db) {
        bf16x8 kf = *(const bf16x8*)(kr + ((db * 32 + h2 * 16) ^ xk));
        sv = __builtin_amdgcn_mfma_f32_32x32x16_bf16(kf, qf[db], sv, 0, 0, 0);
      }
      if (!okv) {
#pragma unroll
        for (int rg = 0; rg < 4; ++rg) {
          f32x4 mk = *(const f32x4*)&Msm[kbk * 32 + rg * 8 + h2 * 4];
          sv[rg * 4 + 0] += mk[0]; sv[rg * 4 + 1] += mk[1];
          sv[rg * 4 + 2] += mk[2]; sv[rg * 4 + 3] += mk[3];
        }
      }
#pragma unroll
      for (int r = 0; r < 16; ++r) sv[r] = fexp2(sv[r]);
      // scalar li via tree-sum
      {
        float t0 = (sv[0] + sv[1]) + (sv[2] + sv[3]);
        float t1 = (sv[4] + sv[5]) + (sv[6] + sv[7]);
        float t2 = (sv[8] + sv[9]) + (sv[10] + sv[11]);
        float t3 = (sv[12] + sv[13]) + (sv[14] + sv[15]);
        li += (t0 + t1) + (t2 + t3);
      }
      uint32_t w0 = cvtpk(sv[0], sv[1]), w1 = cvtpk(sv[2], sv[3]);
      uint32_t w2 = cvtpk(sv[4], sv[5]), w3 = cvtpk(sv[6], sv[7]);
      uint32_t w4 = cvtpk(sv[8], sv[9]), w5 = cvtpk(sv[10], sv[11]);
      uint32_t w6 = cvtpk(sv[12], sv[13]), w7 = cvtpk(sv[14], sv[15]);
      uint32_t x0 = __shfl_xor(w0, 32), x1 = __shfl_xor(w1, 32);
      uint32_t x2 = __shfl_xor(w2, 32), x3 = __shfl_xor(w3, 32);
      uint32_t x4 = __shfl_xor(w4, 32), x5 = __shfl_xor(w5, 32);
      uint32_t x6 = __shfl_xor(w6, 32), x7 = __shfl_xor(w7, 32);
      bf16x8 pf[2];
      {
        union { bf16x8 v; uint32_t u[4]; } u_;
        u_.u[0] = h2 ? x2 : w0; u_.u[1] = h2 ? x3 : w1;
        u_.u[2] = h2 ? w2 : x0; u_.u[3] = h2 ? w3 : x1;
        pf[0] = u_.v;
      }
      {
        union { bf16x8 v; uint32_t u[4]; } u_;
        u_.u[0] = h2 ? x6 : w4; u_.u[1] = h2 ? x7 : w5;
        u_.u[2] = h2 ? w6 : x4; u_.u[3] = h2 ? w7 : x5;
        pf[1] = u_.v;
      }
#pragma unroll
      for (int vb = 0; vb < 2; ++vb) {
        const char* vbase = VsmB + (vb * 32 + lq) * 128;
#pragma unroll
        for (int s = 0; s < 2; ++s) {
          bf16x8 vf = *(const bf16x8*)(vbase + ((kbk * 64 + s * 32 + h2 * 16) ^ vx));
          oacc[vb] = __builtin_amdgcn_mfma_f32_32x32x16_bf16(vf, pf[s], oacc[vb], 0, 0, 0);
        }
      }
    }
    __syncthreads();
  }

  // ---- epilogue: store PARTIAL oacc (bf16, undivided) + li (f32) ----
  li += __shfl_xor(li, 32);

  unsigned short* op = opart + (size_t)sp * ((size_t)MROWS * D_EMB);
  size_t orow = (size_t)(mI * T_SEQ + qrow) * D_EMB + h * 64;
#pragma unroll
  for (int vb = 0; vb < 2; ++vb)
#pragma unroll
    for (int rg = 0; rg < 4; ++rg) {
      uint2 ow;
      ow.x = cvtpk(oacc[vb][rg * 4 + 0], oacc[vb][rg * 4 + 1]);
      ow.y = cvtpk(oacc[vb][rg * 4 + 2], oacc[vb][rg * 4 + 3]);
      *(uint2*)&op[orow + vb * 32 + rg * 8 + h2 * 4] = ow;
    }
  if (h2 == 0)
    lipart[((size_t)sp * MROWS + mI * T_SEQ + qrow) * H_HEADS + h] = li;
}

// ---------------- combine: cc = sum_sp(O_sp) / sum_sp(li_sp), bf16 ----------------
__global__ __launch_bounds__(256) void combine(const unsigned short* __restrict__ opart,
                                               const float* __restrict__ lipart,
                                               unsigned short* __restrict__ cc,
                                               int nsp) {
  int i = blockIdx.x * 256 + threadIdx.x;   // 524288 groups of 8
  int row = i >> 7;                          // 0..4095
  int c8 = i & 127;
  int h = c8 >> 3;
  float lsum = 0.f;
  float acc[8] = {};
#pragma unroll 1
  for (int s = 0; s < nsp; ++s) {
    lsum += lipart[((size_t)s * MROWS + row) * H_HEADS + h];
    size_t off = (size_t)s * MROWS * D_EMB + (size_t)row * D_EMB + c8 * 8;
    us4 a0 = *(const us4*)&opart[off];
    us4 a1 = *(const us4*)&opart[off + 4];
#pragma unroll
    for (int e = 0; e < 4; ++e) { acc[e] += bf2f(a0[e]); acc[4 + e] += bf2f(a1[e]); }
  }
  float inv = 1.f / lsum;
  uint2 o0, o1;
  o0.x = cvtpk(acc[0] * inv, acc[1] * inv);
  o0.y = cvtpk(acc[2] * inv, acc[3] * inv);
  o1.x = cvtpk(acc[4] * inv, acc[5] * inv);
  o1.y = cvtpk(acc[6] * inv, acc[7] * inv);
  size_t off = (size_t)row * D_EMB + c8 * 8;
  *(uint2*)&cc[off] = o0;
  *(uint2*)&cc[off + 4] = o1;
}

extern "C" void kernel_launch(void* const* d_in, const int* in_sizes, int n_in,
                              void* d_out, int out_size, void* d_ws, size_t ws_size,
                              hipStream_t stream) {
  const float* Q  = (const float*)d_in[0];
  const float* K  = (const float*)d_in[1];
  const float* V  = (const float*)d_in[2];
  const int* mask = (const int*)d_in[3];
  const float* Wq = (const float*)d_in[4];
  const float* bq = (const float*)d_in[5];
  const float* Wk = (const float*)d_in[6];
  const float* bk = (const float*)d_in[7];
  const float* Wv = (const float*)d_in[8];
  const float* bv = (const float*)d_in[9];
  const float* Wo = (const float*)d_in[10];
  const float* bo = (const float*)d_in[11];

  uint8_t* ws = (uint8_t*)d_ws;
  const size_t MB = 1u << 20;
  unsigned short* Wq_b = (unsigned short*)(ws + 0 * MB);
  unsigned short* Wk_b = (unsigned short*)(ws + 2 * MB);
  unsigned short* Wv_b = (unsigned short*)(ws + 4 * MB);
  unsigned short* Wo_b = (unsigned short*)(ws + 6 * MB);
  unsigned short* q_b  = (unsigned short*)(ws + 8 * MB);
  unsigned short* k_b  = (unsigned short*)(ws + 16 * MB);
  unsigned short* vt_b = (unsigned short*)(ws + 24 * MB);
  // Qb/Kb/Vb (bf16 GEMM inputs) at 32/40/48 MB are dead after qkv_gemm.
  // opart (nsp x 8MB) starts at 32 MB (nsp=4 spans 32-64 MB; requires ws>=64MB,
  // else nsp=2 spans 32-48 MB). lipart (<=1MB) aliases Wq_b (ws+0): Wq_b is dead
  // after qkv_gemm and NOT read by attn (R14 aliased k_b -> race -> NaN).
  // cc_b aliases q_b (8 MB): written only by combine, after attn's last q read.
  unsigned short* Qb    = (unsigned short*)(ws + 32 * MB);
  unsigned short* Kb    = (unsigned short*)(ws + 40 * MB);
  unsigned short* Vb    = (unsigned short*)(ws + 48 * MB);
  unsigned short* opart = (unsigned short*)(ws + 32 * MB);
  float*          lipart = (float*)(ws + 0 * MB);
  unsigned short* cc_b  = (unsigned short*)(ws + 8 * MB);

  const int nsp = (ws_size >= (size_t)64 * MB) ? 4 : 2;

  cvt_all<<<dim3(16384), dim3(256), 0, stream>>>(Q, K, V, Wq, Wk, Wv, Wo,
                                                 Qb, Kb, Vb, Wq_b, Wk_b, Wv_b, Wo_b);

  qkv_gemm<<<dim3(1536), dim3(256), 0, stream>>>(
      Qb, Kb, Vb, Wq_b, Wk_b, Wv_b, bq, bk, bv, q_b, k_b, vt_b);

  attn_fwd<<<dim3(512 * nsp), dim3(256), 0, stream>>>(
      q_b, k_b, vt_b, mask, opart, lipart, nsp);

  combine<<<dim3(2048), dim3(256), 0, stream>>>(opart, lipart, cc_b, nsp);

  out_gemm<<<dim3(512), dim3(256), 0, stream>>>(
      cc_b, Wo_b, bo, (float*)d_out);
}

// Round 16
// 139.807 us; speedup vs baseline: 1.0455x; 1.0455x over previous
//
#include <hip/hip_runtime.h>
#include <cstdint>
#include <cstddef>

#define T_SEQ 2048
#define D_EMB 1024
#define H_HEADS 16
#define MROWS 4096
// scale * log2(e): softmax computed in exp2 domain; folded into q projection
#define SC2 (0.03125f * 1.44269504f)
#define MASKNEG (-1e30f)

typedef __attribute__((ext_vector_type(8))) short bf16x8;
typedef __attribute__((ext_vector_type(4))) float f32x4;
typedef __attribute__((ext_vector_type(16))) float f32x16;
typedef __attribute__((ext_vector_type(4))) unsigned short us4;

__device__ __forceinline__ unsigned short f2bf(float f) {
  union { float f; uint32_t u; } v; v.f = f;
  uint32_t u = v.u;
  return (unsigned short)((u + 0x7FFFu + ((u >> 16) & 1u)) >> 16);
}

__device__ __forceinline__ uint32_t cvtpk(float lo, float hi) {
  uint32_t r;
  asm("v_cvt_pk_bf16_f32 %0, %1, %2" : "=v"(r) : "v"(lo), "v"(hi));
  return r;
}

__device__ __forceinline__ float fexp2(float x) {
  float r;
  asm("v_exp_f32 %0, %1" : "=v"(r) : "v"(x));
  return r;
}

__device__ __forceinline__ float bf2f(unsigned short u) {
  union { uint32_t u; float f; } v; v.u = ((uint32_t)u) << 16;
  return v.f;
}

__device__ __forceinline__ void gl16(const void* g, void* l) {
  __builtin_amdgcn_global_load_lds(
      (const __attribute__((address_space(1))) unsigned int*)g,
      (__attribute__((address_space(3))) unsigned int*)l, 16, 0, 0);
}

// ---------------- fused fp32 -> bf16 (3 inputs + 4 weights, one dispatch) ----------------
__global__ __launch_bounds__(256) void cvt_all(
    const float* __restrict__ Q, const float* __restrict__ K, const float* __restrict__ V,
    const float* __restrict__ Wq, const float* __restrict__ Wk,
    const float* __restrict__ Wv, const float* __restrict__ Wo,
    unsigned short* __restrict__ Qb, unsigned short* __restrict__ Kb,
    unsigned short* __restrict__ Vb,
    unsigned short* __restrict__ Wqb, unsigned short* __restrict__ Wkb,
    unsigned short* __restrict__ Wvb, unsigned short* __restrict__ Wob) {
  int i = blockIdx.x * 256 + threadIdx.x;
  const float* src;
  unsigned short* dst;
  int j;
  if (i < 3145728) {
    int s = i >> 20;
    j = i & 1048575;
    src = (s == 0) ? Q : (s == 1) ? K : V;
    dst = (s == 0) ? Qb : (s == 1) ? Kb : Vb;
  } else {
    int k = i - 3145728;
    int s = k >> 18;
    j = k & 262143;
    src = (s == 0) ? Wq : (s == 1) ? Wk : (s == 2) ? Wv : Wo;
    dst = (s == 0) ? Wqb : (s == 1) ? Wkb : (s == 2) ? Wvb : Wob;
  }
  float4 f = ((const float4*)src)[j];
  us4 o;
  o[0] = f2bf(f.x); o[1] = f2bf(f.y); o[2] = f2bf(f.z); o[3] = f2bf(f.w);
  ((us4*)dst)[j] = o;
}

// ---------------- fused QKV projection GEMM (BM=128 BN=64, 6 blocks/CU) ----------------
// 1D grid 1536 blocks, XCD-swizzled bijectively: swz = (bid&7)*192 + bid>>3;
// bx=swz&15 (16 col-blocks of 64), by=(swz>>4)&31, z=swz>>9. Wave layout =
// out_gemm's proven 4 waves x (32x64), acc[2][4]. dbuf 2-phase K-loop, 24KB LDS.
// z==0 (q) output pre-scaled by SC2 so attention softmax needs no per-logit scale.
__global__ __launch_bounds__(256) void qkv_gemm(
    const unsigned short* __restrict__ Qb, const unsigned short* __restrict__ Kb,
    const unsigned short* __restrict__ Vb,
    const unsigned short* __restrict__ Wqb, const unsigned short* __restrict__ Wkb,
    const unsigned short* __restrict__ Wvb,
    const float* __restrict__ bq, const float* __restrict__ bk, const float* __restrict__ bv,
    unsigned short* __restrict__ qo, unsigned short* __restrict__ ko,
    unsigned short* __restrict__ vto) {
  const int swz = (blockIdx.x & 7) * 192 + (blockIdx.x >> 3);
  const int bx = swz & 15, by = (swz >> 4) & 31, z = swz >> 9;
  const unsigned short* A = (z == 0) ? Qb : (z == 1) ? Kb : Vb;
  const unsigned short* W = (z == 0) ? Wqb : (z == 1) ? Wkb : Wvb;
  const float* bias = (z == 0) ? bq : (z == 1) ? bk : bv;

  __shared__ __align__(16) unsigned short Asm[2][128 * 32];
  __shared__ __align__(16) unsigned short Bsm[2][64 * 32];

  const int tid = threadIdx.x;
  const int lane = tid & 63, w = tid >> 6;
  const int fq = lane >> 4, fr = lane & 15;
  const int brow = by * 128, bcol = bx * 64;
  const int wr = w * 32;

  f32x4 acc[2][4] = {};

#define QKV_STAGE(buf, k0)                                                     \
  {                                                                            \
    _Pragma("unroll") for (int it = 0; it < 2; ++it) {                         \
      int idx = it * 256 + tid;                                                \
      int row = idx >> 2, ce = (idx & 3) * 8;                                  \
      gl16(&A[(size_t)(brow + row) * D_EMB + (k0) + ce],                       \
           (char*)Asm[buf] + idx * 16);                                        \
    }                                                                          \
    {                                                                          \
      int row = tid >> 2, ce = (tid & 3) * 8;                                  \
      gl16(&W[(size_t)(bcol + row) * D_EMB + (k0) + ce],                       \
           (char*)Bsm[buf] + tid * 16);                                        \
    }                                                                          \
  }

#define QKV_COMPUTE(buf)                                                       \
  {                                                                            \
    bf16x8 af[2], bfr[4];                                                      \
    _Pragma("unroll") for (int i = 0; i < 2; ++i)                              \
        af[i] = *(const bf16x8*)((const char*)Asm[buf] +                       \
                                 (wr + i * 16 + fr) * 64 + fq * 16);           \
    _Pragma("unroll") for (int j = 0; j < 4; ++j)                              \
        bfr[j] = *(const bf16x8*)((const char*)Bsm[buf] +                      \
                                  (j * 16 + fr) * 64 + fq * 16);               \
    _Pragma("unroll") for (int i = 0; i < 2; ++i)                              \
        _Pragma("unroll") for (int j = 0; j < 4; ++j)                          \
            acc[i][j] = __builtin_amdgcn_mfma_f32_16x16x32_bf16(               \
                af[i], bfr[j], acc[i][j], 0, 0, 0);                            \
  }

  QKV_STAGE(0, 0);
  __syncthreads();
#pragma unroll 1
  for (int t = 0; t < 32; t += 2) {
    QKV_STAGE(1, (t + 1) * 32);
    QKV_COMPUTE(0);
    __syncthreads();
    if (t + 2 < 32) QKV_STAGE(0, (t + 2) * 32);
    QKV_COMPUTE(1);
    __syncthreads();
  }

  // epilogue
#pragma unroll
  for (int i = 0; i < 2; ++i) {
#pragma unroll
    for (int j = 0; j < 4; ++j) {
      int r0 = brow + wr + i * 16 + fq * 4;
      int cc = bcol + j * 16 + fr;
      float bb = bias[cc];
      if (z < 2) {
        unsigned short* O = (z == 0) ? qo : ko;
        float sc = (z == 0) ? SC2 : 1.0f;
#pragma unroll
        for (int q = 0; q < 4; ++q)
          O[(size_t)(r0 + q) * D_EMB + cc] = f2bf((acc[i][j][q] + bb) * sc);
      } else {
        int hh = cc >> 6, dd = cc & 63;
        int mm = r0 >> 11, tt = r0 & 2047;
        us4 pk;
#pragma unroll
        for (int q = 0; q < 4; ++q) pk[q] = f2bf(acc[i][j][q] + bb);
        *(us4*)&vto[((size_t)((mm * H_HEADS + hh) * 64 + dd)) * T_SEQ + tt] = pk;
      }
    }
  }
}

// ---------------- output projection GEMM ----------------
__global__ __launch_bounds__(256) void out_gemm(const unsigned short* __restrict__ Ab,
                                                const unsigned short* __restrict__ Wb,
                                                const float* __restrict__ bias,
                                                float* __restrict__ Out) {
  const int swz = (blockIdx.x & 7) * 64 + (blockIdx.x >> 3);
  const int bx = swz & 15, by = swz >> 4;

  __shared__ __align__(16) unsigned short Asm[2][128 * 32];
  __shared__ __align__(16) unsigned short Bsm[2][64 * 32];
  const int tid = threadIdx.x;
  const int lane = tid & 63, w = tid >> 6;
  const int fq = lane >> 4, fr = lane & 15;
  const int brow = by * 128, bcol = bx * 64;
  const int wr = w * 32;

  f32x4 acc[2][4] = {};

#define OUT_STAGE(buf, k0)                                                     \
  {                                                                            \
    _Pragma("unroll") for (int it = 0; it < 2; ++it) {                         \
      int idx = it * 256 + tid;                                                \
      int row = idx >> 2, ce = (idx & 3) * 8;                                  \
      gl16(&Ab[(size_t)(brow + row) * D_EMB + (k0) + ce],                      \
           (char*)Asm[buf] + idx * 16);                                        \
    }                                                                          \
    {                                                                          \
      int row = tid >> 2, ce = (tid & 3) * 8;                                  \
      gl16(&Wb[(size_t)(bcol + row) * D_EMB + (k0) + ce],                      \
           (char*)Bsm[buf] + tid * 16);                                        \
    }                                                                          \
  }

#define OUT_COMPUTE(buf)                                                       \
  {                                                                            \
    bf16x8 af[2], bfr[4];                                                      \
    _Pragma("unroll") for (int i = 0; i < 2; ++i)                              \
        af[i] = *(const bf16x8*)((const char*)Asm[buf] +                       \
                                 (wr + i * 16 + fr) * 64 + fq * 16);           \
    _Pragma("unroll") for (int j = 0; j < 4; ++j)                              \
        bfr[j] = *(const bf16x8*)((const char*)Bsm[buf] +                      \
                                  (j * 16 + fr) * 64 + fq * 16);               \
    _Pragma("unroll") for (int i = 0; i < 2; ++i)                              \
        _Pragma("unroll") for (int j = 0; j < 4; ++j)                          \
            acc[i][j] = __builtin_amdgcn_mfma_f32_16x16x32_bf16(               \
                af[i], bfr[j], acc[i][j], 0, 0, 0);                            \
  }

  OUT_STAGE(0, 0);
  __syncthreads();
#pragma unroll 1
  for (int t = 0; t < 32; t += 2) {
    OUT_STAGE(1, (t + 1) * 32);
    OUT_COMPUTE(0);
    __syncthreads();
    if (t + 2 < 32) OUT_STAGE(0, (t + 2) * 32);
    OUT_COMPUTE(1);
    __syncthreads();
  }

#pragma unroll
  for (int i = 0; i < 2; ++i)
#pragma unroll
    for (int j = 0; j < 4; ++j) {
      int r0 = brow + wr + i * 16 + fq * 4;
      int cc = bcol + j * 16 + fr;
      float bb = bias[cc];
#pragma unroll
      for (int q = 0; q < 4; ++q)
        Out[(size_t)(r0 + q) * D_EMB + cc] = acc[i][j][q] + bb;
    }
}

// ---------------- Flash attention (grid K-split, 32x32 MFMA, single-buf) ----------------
// 1D grid 1024 blocks XCD-swizzled; block = 256 thr (4 waves x 32 q). sp selects
// key half. Scalar li + launch_bounds(256,4). Partial O + li out; combine merges.
__global__ __launch_bounds__(256, 4) void attn_fwd(const unsigned short* __restrict__ qb,
                                                   const unsigned short* __restrict__ kb,
                                                   const unsigned short* __restrict__ vtb,
                                                   const int* __restrict__ maskg,
                                                   unsigned short* __restrict__ opart,
                                                   float* __restrict__ lipart) {
  const int swzb = (blockIdx.x & 7) * 128 + (blockIdx.x >> 3);
  const int qt = swzb & 15, h = (swzb >> 4) & 15, mI = (swzb >> 8) & 1, sp = swzb >> 9;
  const int tid = threadIdx.x;
  const int lane = tid & 63, w = tid >> 6;
  const int lq = lane & 31, h2 = lane >> 5;
  const int xk = (lq & 7) << 4;
  const int vx = (lq & 7) << 4;

  __shared__ __align__(16) unsigned short Ksm[128 * 64];  // [key][d], swizzled
  __shared__ __align__(16) unsigned short Vsm[64 * 128];  // [d][t], swizzled
  __shared__ __align__(16) float Msm[128];
  __shared__ int moks[16];

  char* KsmB = (char*)Ksm;
  char* VsmB = (char*)Vsm;

  // ---- per-(m,tile) all-ones mask flags (once per block) ----
  if (tid < 16) moks[tid] = 1;
  __syncthreads();
  {
    int bad = 0;
    const int4* mg = (const int4*)&maskg[mI * T_SEQ + tid * 8];
    int4 a = mg[0], b = mg[1];
    bad |= (a.x == 0) | (a.y == 0) | (a.z == 0) | (a.w == 0);
    bad |= (b.x == 0) | (b.y == 0) | (b.z == 0) | (b.w == 0);
    if (bad) moks[tid >> 4] = 0;
  }
  __syncthreads();
  int okbits = 0;
#pragma unroll
  for (int i = 0; i < 16; ++i) okbits |= (moks[i] != 0) << i;

  // ---- Q fragments in registers (B-frag: col=q=lq, k=d) ----
  const int qrow = qt * 128 + w * 32 + lq;
  bf16x8 qf[4];
#pragma unroll
  for (int db = 0; db < 4; ++db)
    qf[db] = *(const bf16x8*)&qb[((size_t)(mI * T_SEQ) + qrow) * D_EMB + h * 64 + db * 16 + h2 * 8];

  f32x16 oacc[2] = {};
  float li = 0.f;

  const unsigned short* kpan = kb + (size_t)(mI * T_SEQ) * D_EMB + h * 64;
  const unsigned short* vpan = vtb + (size_t)(mI * H_HEADS + h) * 64 * T_SEQ;

#pragma unroll 1
  for (int t = sp * 8; t < sp * 8 + 8; ++t) {
    const int okv = (okbits >> t) & 1;
    const int k0s = t * 128;
    // ---- stage K [128][64] + Vt [64][128] (single buffer) ----
#pragma unroll
    for (int it = 0; it < 4; ++it) {
      int idx = it * 256 + tid;
      int row = idx >> 3;
      int sb = ((idx & 7) * 16) ^ ((row & 7) << 4);
      gl16(kpan + (size_t)(k0s + row) * D_EMB + (sb >> 1), KsmB + idx * 16);
    }
#pragma unroll
    for (int it = 0; it < 4; ++it) {
      int idx = it * 256 + tid;
      int row = idx >> 4;
      int sb = ((idx & 15) * 16) ^ ((row & 7) << 4);
      gl16(vpan + (size_t)row * T_SEQ + k0s + (sb >> 1), VsmB + idx * 16);
    }
    if (!okv && tid < 128)
      Msm[tid] = (maskg[mI * T_SEQ + k0s + tid] == 0) ? MASKNEG : 0.f;
    __syncthreads();

    // ---- 4 key-blocks of 32 ----
#pragma unroll 1
    for (int kbk = 0; kbk < 4; ++kbk) {
      f32x16 sv = {};
      const char* kr = KsmB + (kbk * 32 + lq) * 128;
#pragma unroll
      for (int db = 0; db < 4; ++db) {
        bf16x8 kf = *(const bf16x8*)(kr + ((db * 32 + h2 * 16) ^ xk));
        sv = __builtin_amdgcn_mfma_f32_32x32x16_bf16(kf, qf[db], sv, 0, 0, 0);
      }
      if (!okv) {
#pragma unroll
        for (int rg = 0; rg < 4; ++rg) {
          f32x4 mk = *(const f32x4*)&Msm[kbk * 32 + rg * 8 + h2 * 4];
          sv[rg * 4 + 0] += mk[0]; sv[rg * 4 + 1] += mk[1];
          sv[rg * 4 + 2] += mk[2]; sv[rg * 4 + 3] += mk[3];
        }
      }
#pragma unroll
      for (int r = 0; r < 16; ++r) sv[r] = fexp2(sv[r]);
      // scalar li via tree-sum
      {
        float t0 = (sv[0] + sv[1]) + (sv[2] + sv[3]);
        float t1 = (sv[4] + sv[5]) + (sv[6] + sv[7]);
        float t2 = (sv[8] + sv[9]) + (sv[10] + sv[11]);
        float t3 = (sv[12] + sv[13]) + (sv[14] + sv[15]);
        li += (t0 + t1) + (t2 + t3);
      }
      uint32_t w0 = cvtpk(sv[0], sv[1]), w1 = cvtpk(sv[2], sv[3]);
      uint32_t w2 = cvtpk(sv[4], sv[5]), w3 = cvtpk(sv[6], sv[7]);
      uint32_t w4 = cvtpk(sv[8], sv[9]), w5 = cvtpk(sv[10], sv[11]);
      uint32_t w6 = cvtpk(sv[12], sv[13]), w7 = cvtpk(sv[14], sv[15]);
      uint32_t x0 = __shfl_xor(w0, 32), x1 = __shfl_xor(w1, 32);
      uint32_t x2 = __shfl_xor(w2, 32), x3 = __shfl_xor(w3, 32);
      uint32_t x4 = __shfl_xor(w4, 32), x5 = __shfl_xor(w5, 32);
      uint32_t x6 = __shfl_xor(w6, 32), x7 = __shfl_xor(w7, 32);
      bf16x8 pf[2];
      {
        union { bf16x8 v; uint32_t u[4]; } u_;
        u_.u[0] = h2 ? x2 : w0; u_.u[1] = h2 ? x3 : w1;
        u_.u[2] = h2 ? w2 : x0; u_.u[3] = h2 ? w3 : x1;
        pf[0] = u_.v;
      }
      {
        union { bf16x8 v; uint32_t u[4]; } u_;
        u_.u[0] = h2 ? x6 : w4; u_.u[1] = h2 ? x7 : w5;
        u_.u[2] = h2 ? w6 : x4; u_.u[3] = h2 ? w7 : x5;
        pf[1] = u_.v;
      }
#pragma unroll
      for (int vb = 0; vb < 2; ++vb) {
        const char* vbase = VsmB + (vb * 32 + lq) * 256;
#pragma unroll
        for (int s = 0; s < 2; ++s) {
          bf16x8 vf = *(const bf16x8*)(vbase + ((kbk * 64 + s * 32 + h2 * 16) ^ vx));
          oacc[vb] = __builtin_amdgcn_mfma_f32_32x32x16_bf16(vf, pf[s], oacc[vb], 0, 0, 0);
        }
      }
    }
    __syncthreads();
  }

  // ---- epilogue: store PARTIAL oacc (bf16, undivided) + li (f32) ----
  li += __shfl_xor(li, 32);

  unsigned short* op = opart + (size_t)sp * ((size_t)MROWS * D_EMB);
  size_t orow = (size_t)(mI * T_SEQ + qrow) * D_EMB + h * 64;
#pragma unroll
  for (int vb = 0; vb < 2; ++vb)
#pragma unroll
    for (int rg = 0; rg < 4; ++rg) {
      uint2 ow;
      ow.x = cvtpk(oacc[vb][rg * 4 + 0], oacc[vb][rg * 4 + 1]);
      ow.y = cvtpk(oacc[vb][rg * 4 + 2], oacc[vb][rg * 4 + 3]);
      *(uint2*)&op[orow + vb * 32 + rg * 8 + h2 * 4] = ow;
    }
  if (h2 == 0)
    lipart[((size_t)sp * MROWS + mI * T_SEQ + qrow) * H_HEADS + h] = li;
}

// ---------------- combine: cc = (O0 + O1) / (li0 + li1), bf16 ----------------
__global__ __launch_bounds__(256) void combine(const unsigned short* __restrict__ opart,
                                               const float* __restrict__ lipart,
                                               unsigned short* __restrict__ cc) {
  int i = blockIdx.x * 256 + threadIdx.x;   // 524288 groups of 8
  int row = i >> 7;                          // 0..4095
  int c8 = i & 127;
  int h = c8 >> 3;
  float l0 = lipart[(size_t)row * H_HEADS + h];
  float l1 = lipart[((size_t)MROWS + row) * H_HEADS + h];
  float inv = 1.f / (l0 + l1);
  size_t off = (size_t)row * D_EMB + c8 * 8;
  us4 a0 = *(const us4*)&opart[off];
  us4 a1 = *(const us4*)&opart[off + 4];
  us4 b0 = *(const us4*)&opart[(size_t)MROWS * D_EMB + off];
  us4 b1 = *(const us4*)&opart[(size_t)MROWS * D_EMB + off + 4];
  uint2 o0, o1;
  o0.x = cvtpk((bf2f(a0[0]) + bf2f(b0[0])) * inv, (bf2f(a0[1]) + bf2f(b0[1])) * inv);
  o0.y = cvtpk((bf2f(a0[2]) + bf2f(b0[2])) * inv, (bf2f(a0[3]) + bf2f(b0[3])) * inv);
  o1.x = cvtpk((bf2f(a1[0]) + bf2f(b1[0])) * inv, (bf2f(a1[1]) + bf2f(b1[1])) * inv);
  o1.y = cvtpk((bf2f(a1[2]) + bf2f(b1[2])) * inv, (bf2f(a1[3]) + bf2f(b1[3])) * inv);
  *(uint2*)&cc[off] = o0;
  *(uint2*)&cc[off + 4] = o1;
}

extern "C" void kernel_launch(void* const* d_in, const int* in_sizes, int n_in,
                              void* d_out, int out_size, void* d_ws, size_t ws_size,
                              hipStream_t stream) {
  const float* Q  = (const float*)d_in[0];
  const float* K  = (const float*)d_in[1];
  const float* V  = (const float*)d_in[2];
  const int* mask = (const int*)d_in[3];
  const float* Wq = (const float*)d_in[4];
  const float* bq = (const float*)d_in[5];
  const float* Wk = (const float*)d_in[6];
  const float* bk = (const float*)d_in[7];
  const float* Wv = (const float*)d_in[8];
  const float* bv = (const float*)d_in[9];
  const float* Wo = (const float*)d_in[10];
  const float* bo = (const float*)d_in[11];

  uint8_t* ws = (uint8_t*)d_ws;
  const size_t MB = 1u << 20;
  unsigned short* Wq_b = (unsigned short*)(ws + 0 * MB);
  unsigned short* Wk_b = (unsigned short*)(ws + 2 * MB);
  unsigned short* Wv_b = (unsigned short*)(ws + 4 * MB);
  unsigned short* Wo_b = (unsigned short*)(ws + 6 * MB);
  unsigned short* q_b  = (unsigned short*)(ws + 8 * MB);
  unsigned short* k_b  = (unsigned short*)(ws + 16 * MB);
  unsigned short* vt_b = (unsigned short*)(ws + 24 * MB);
  // Qb/Kb/Vb (bf16 GEMM inputs) at 32/40/48 MB are dead after qkv_gemm:
  // opart (2x8MB) aliases Qb+Kb; cc_b aliases Vb; lipart fresh at 56 MB.
  unsigned short* Qb    = (unsigned short*)(ws + 32 * MB);
  unsigned short* Kb    = (unsigned short*)(ws + 40 * MB);
  unsigned short* Vb    = (unsigned short*)(ws + 48 * MB);
  unsigned short* opart = (unsigned short*)(ws + 32 * MB);
  unsigned short* cc_b  = (unsigned short*)(ws + 48 * MB);
  float*          lipart = (float*)(ws + 56 * MB);

  cvt_all<<<dim3(16384), dim3(256), 0, stream>>>(Q, K, V, Wq, Wk, Wv, Wo,
                                                 Qb, Kb, Vb, Wq_b, Wk_b, Wv_b, Wo_b);

  qkv_gemm<<<dim3(1536), dim3(256), 0, stream>>>(
      Qb, Kb, Vb, Wq_b, Wk_b, Wv_b, bq, bk, bv, q_b, k_b, vt_b);

  attn_fwd<<<dim3(1024), dim3(256), 0, stream>>>(
      q_b, k_b, vt_b, mask, opart, lipart);

  combine<<<dim3(2048), dim3(256), 0, stream>>>(opart, lipart, cc_b);

  out_gemm<<<dim3(512), dim3(256), 0, stream>>>(
      cc_b, Wo_b, bo, (float*)d_out);
}

// Round 18
// 139.610 us; speedup vs baseline: 1.0469x; 1.0014x over previous
//
#include <hip/hip_runtime.h>
#include <cstdint>
#include <cstddef>

#define T_SEQ 2048
#define D_EMB 1024
#define H_HEADS 16
#define MROWS 4096
// scale * log2(e): softmax computed in exp2 domain; folded into q projection
#define SC2 (0.03125f * 1.44269504f)
#define MASKNEG (-1e30f)

typedef __attribute__((ext_vector_type(8))) short bf16x8;
typedef __attribute__((ext_vector_type(4))) float f32x4;
typedef __attribute__((ext_vector_type(16))) float f32x16;
typedef __attribute__((ext_vector_type(4))) unsigned short us4;

__device__ __forceinline__ unsigned short f2bf(float f) {
  union { float f; uint32_t u; } v; v.f = f;
  uint32_t u = v.u;
  return (unsigned short)((u + 0x7FFFu + ((u >> 16) & 1u)) >> 16);
}

__device__ __forceinline__ uint32_t cvtpk(float lo, float hi) {
  uint32_t r;
  asm("v_cvt_pk_bf16_f32 %0, %1, %2" : "=v"(r) : "v"(lo), "v"(hi));
  return r;
}

__device__ __forceinline__ float fexp2(float x) {
  float r;
  asm("v_exp_f32 %0, %1" : "=v"(r) : "v"(x));
  return r;
}

__device__ __forceinline__ float bf2f(unsigned short u) {
  union { uint32_t u; float f; } v; v.u = ((uint32_t)u) << 16;
  return v.f;
}

__device__ __forceinline__ void gl16(const void* g, void* l) {
  __builtin_amdgcn_global_load_lds(
      (const __attribute__((address_space(1))) unsigned int*)g,
      (__attribute__((address_space(3))) unsigned int*)l, 16, 0, 0);
}

// ---------------- fused fp32 -> bf16 (3 inputs + 4 weights, one dispatch) ----------------
__global__ __launch_bounds__(256) void cvt_all(
    const float* __restrict__ Q, const float* __restrict__ K, const float* __restrict__ V,
    const float* __restrict__ Wq, const float* __restrict__ Wk,
    const float* __restrict__ Wv, const float* __restrict__ Wo,
    unsigned short* __restrict__ Qb, unsigned short* __restrict__ Kb,
    unsigned short* __restrict__ Vb,
    unsigned short* __restrict__ Wqb, unsigned short* __restrict__ Wkb,
    unsigned short* __restrict__ Wvb, unsigned short* __restrict__ Wob) {
  int i = blockIdx.x * 256 + threadIdx.x;
  const float* src;
  unsigned short* dst;
  int j;
  if (i < 3145728) {
    int s = i >> 20;
    j = i & 1048575;
    src = (s == 0) ? Q : (s == 1) ? K : V;
    dst = (s == 0) ? Qb : (s == 1) ? Kb : Vb;
  } else {
    int k = i - 3145728;
    int s = k >> 18;
    j = k & 262143;
    src = (s == 0) ? Wq : (s == 1) ? Wk : (s == 2) ? Wv : Wo;
    dst = (s == 0) ? Wqb : (s == 1) ? Wkb : (s == 2) ? Wvb : Wob;
  }
  float4 f = ((const float4*)src)[j];
  us4 o;
  o[0] = f2bf(f.x); o[1] = f2bf(f.y); o[2] = f2bf(f.z); o[3] = f2bf(f.w);
  ((us4*)dst)[j] = o;
}

// ---------------- fused QKV projection GEMM (BM=128 BN=64, 6 blocks/CU) ----------------
// 1D grid 1536 blocks, XCD-swizzled bijectively: swz = (bid&7)*192 + bid>>3;
// bx=swz&15 (16 col-blocks of 64), by=(swz>>4)&31, z=swz>>9. Wave layout =
// out_gemm's proven 4 waves x (32x64), acc[2][4]. dbuf 2-phase K-loop, 24KB LDS.
// z==0 (q) output pre-scaled by SC2 so attention softmax needs no per-logit scale.
__global__ __launch_bounds__(256) void qkv_gemm(
    const unsigned short* __restrict__ Qb, const unsigned short* __restrict__ Kb,
    const unsigned short* __restrict__ Vb,
    const unsigned short* __restrict__ Wqb, const unsigned short* __restrict__ Wkb,
    const unsigned short* __restrict__ Wvb,
    const float* __restrict__ bq, const float* __restrict__ bk, const float* __restrict__ bv,
    unsigned short* __restrict__ qo, unsigned short* __restrict__ ko,
    unsigned short* __restrict__ vto) {
  const int swz = (blockIdx.x & 7) * 192 + (blockIdx.x >> 3);
  const int bx = swz & 15, by = (swz >> 4) & 31, z = swz >> 9;
  const unsigned short* A = (z == 0) ? Qb : (z == 1) ? Kb : Vb;
  const unsigned short* W = (z == 0) ? Wqb : (z == 1) ? Wkb : Wvb;
  const float* bias = (z == 0) ? bq : (z == 1) ? bk : bv;

  __shared__ __align__(16) unsigned short Asm[2][128 * 32];
  __shared__ __align__(16) unsigned short Bsm[2][64 * 32];

  const int tid = threadIdx.x;
  const int lane = tid & 63, w = tid >> 6;
  const int fq = lane >> 4, fr = lane & 15;
  const int brow = by * 128, bcol = bx * 64;
  const int wr = w * 32;

  f32x4 acc[2][4] = {};

#define QKV_STAGE(buf, k0)                                                     \
  {                                                                            \
    _Pragma("unroll") for (int it = 0; it < 2; ++it) {                         \
      int idx = it * 256 + tid;                                                \
      int row = idx >> 2, ce = (idx & 3) * 8;                                  \
      gl16(&A[(size_t)(brow + row) * D_EMB + (k0) + ce],                       \
           (char*)Asm[buf] + idx * 16);                                        \
    }                                                                          \
    {                                                                          \
      int row = tid >> 2, ce = (tid & 3) * 8;                                  \
      gl16(&W[(size_t)(bcol + row) * D_EMB + (k0) + ce],                       \
           (char*)Bsm[buf] + tid * 16);                                        \
    }                                                                          \
  }

#define QKV_COMPUTE(buf)                                                       \
  {                                                                            \
    bf16x8 af[2], bfr[4];                                                      \
    _Pragma("unroll") for (int i = 0; i < 2; ++i)                              \
        af[i] = *(const bf16x8*)((const char*)Asm[buf] +                       \
                                 (wr + i * 16 + fr) * 64 + fq * 16);           \
    _Pragma("unroll") for (int j = 0; j < 4; ++j)                              \
        bfr[j] = *(const bf16x8*)((const char*)Bsm[buf] +                      \
                                  (j * 16 + fr) * 64 + fq * 16);               \
    _Pragma("unroll") for (int i = 0; i < 2; ++i)                              \
        _Pragma("unroll") for (int j = 0; j < 4; ++j)                          \
            acc[i][j] = __builtin_amdgcn_mfma_f32_16x16x32_bf16(               \
                af[i], bfr[j], acc[i][j], 0, 0, 0);                            \
  }

  QKV_STAGE(0, 0);
  __syncthreads();
#pragma unroll 1
  for (int t = 0; t < 32; t += 2) {
    QKV_STAGE(1, (t + 1) * 32);
    QKV_COMPUTE(0);
    __syncthreads();
    if (t + 2 < 32) QKV_STAGE(0, (t + 2) * 32);
    QKV_COMPUTE(1);
    __syncthreads();
  }

  // epilogue
#pragma unroll
  for (int i = 0; i < 2; ++i) {
#pragma unroll
    for (int j = 0; j < 4; ++j) {
      int r0 = brow + wr + i * 16 + fq * 4;
      int cc = bcol + j * 16 + fr;
      float bb = bias[cc];
      if (z < 2) {
        unsigned short* O = (z == 0) ? qo : ko;
        float sc = (z == 0) ? SC2 : 1.0f;
#pragma unroll
        for (int q = 0; q < 4; ++q)
          O[(size_t)(r0 + q) * D_EMB + cc] = f2bf((acc[i][j][q] + bb) * sc);
      } else {
        int hh = cc >> 6, dd = cc & 63;
        int mm = r0 >> 11, tt = r0 & 2047;
        us4 pk;
#pragma unroll
        for (int q = 0; q < 4; ++q) pk[q] = f2bf(acc[i][j][q] + bb);
        *(us4*)&vto[((size_t)((mm * H_HEADS + hh) * 64 + dd)) * T_SEQ + tt] = pk;
      }
    }
  }
}

// ---------------- output projection GEMM ----------------
__global__ __launch_bounds__(256) void out_gemm(const unsigned short* __restrict__ Ab,
                                                const unsigned short* __restrict__ Wb,
                                                const float* __restrict__ bias,
                                                float* __restrict__ Out) {
  const int swz = (blockIdx.x & 7) * 64 + (blockIdx.x >> 3);
  const int bx = swz & 15, by = swz >> 4;

  __shared__ __align__(16) unsigned short Asm[2][128 * 32];
  __shared__ __align__(16) unsigned short Bsm[2][64 * 32];
  const int tid = threadIdx.x;
  const int lane = tid & 63, w = tid >> 6;
  const int fq = lane >> 4, fr = lane & 15;
  const int brow = by * 128, bcol = bx * 64;
  const int wr = w * 32;

  f32x4 acc[2][4] = {};

#define OUT_STAGE(buf, k0)                                                     \
  {                                                                            \
    _Pragma("unroll") for (int it = 0; it < 2; ++it) {                         \
      int idx = it * 256 + tid;                                                \
      int row = idx >> 2, ce = (idx & 3) * 8;                                  \
      gl16(&Ab[(size_t)(brow + row) * D_EMB + (k0) + ce],                      \
           (char*)Asm[buf] + idx * 16);                                        \
    }                                                                          \
    {                                                                          \
      int row = tid >> 2, ce = (tid & 3) * 8;                                  \
      gl16(&Wb[(size_t)(bcol + row) * D_EMB + (k0) + ce],                      \
           (char*)Bsm[buf] + tid * 16);                                        \
    }                                                                          \
  }

#define OUT_COMPUTE(buf)                                                       \
  {                                                                            \
    bf16x8 af[2], bfr[4];                                                      \
    _Pragma("unroll") for (int i = 0; i < 2; ++i)                              \
        af[i] = *(const bf16x8*)((const char*)Asm[buf] +                       \
                                 (wr + i * 16 + fr) * 64 + fq * 16);           \
    _Pragma("unroll") for (int j = 0; j < 4; ++j)                              \
        bfr[j] = *(const bf16x8*)((const char*)Bsm[buf] +                      \
                                  (j * 16 + fr) * 64 + fq * 16);               \
    _Pragma("unroll") for (int i = 0; i < 2; ++i)                              \
        _Pragma("unroll") for (int j = 0; j < 4; ++j)                          \
            acc[i][j] = __builtin_amdgcn_mfma_f32_16x16x32_bf16(               \
                af[i], bfr[j], acc[i][j], 0, 0, 0);                            \
  }

  OUT_STAGE(0, 0);
  __syncthreads();
#pragma unroll 1
  for (int t = 0; t < 32; t += 2) {
    OUT_STAGE(1, (t + 1) * 32);
    OUT_COMPUTE(0);
    __syncthreads();
    if (t + 2 < 32) OUT_STAGE(0, (t + 2) * 32);
    OUT_COMPUTE(1);
    __syncthreads();
  }

#pragma unroll
  for (int i = 0; i < 2; ++i)
#pragma unroll
    for (int j = 0; j < 4; ++j) {
      int r0 = brow + wr + i * 16 + fq * 4;
      int cc = bcol + j * 16 + fr;
      float bb = bias[cc];
#pragma unroll
      for (int q = 0; q < 4; ++q)
        Out[(size_t)(r0 + q) * D_EMB + cc] = acc[i][j][q] + bb;
    }
}

// ---------------- Flash attention (grid K-split, 32x32 MFMA, single-buf) ----------------
// 1D grid 1024 blocks XCD-swizzled; block = 256 thr (4 waves x 32 q). sp selects
// key half. Scalar li + launch_bounds(256,4). Partial O + li out; combine merges.
__global__ __launch_bounds__(256, 4) void attn_fwd(const unsigned short* __restrict__ qb,
                                                   const unsigned short* __restrict__ kb,
                                                   const unsigned short* __restrict__ vtb,
                                                   const int* __restrict__ maskg,
                                                   unsigned short* __restrict__ opart,
                                                   float* __restrict__ lipart) {
  const int swzb = (blockIdx.x & 7) * 128 + (blockIdx.x >> 3);
  const int qt = swzb & 15, h = (swzb >> 4) & 15, mI = (swzb >> 8) & 1, sp = swzb >> 9;
  const int tid = threadIdx.x;
  const int lane = tid & 63, w = tid >> 6;
  const int lq = lane & 31, h2 = lane >> 5;
  const int xk = (lq & 7) << 4;
  const int vx = (lq & 7) << 4;

  __shared__ __align__(16) unsigned short Ksm[128 * 64];  // [key][d], swizzled
  __shared__ __align__(16) unsigned short Vsm[64 * 128];  // [d][t], swizzled
  __shared__ __align__(16) float Msm[128];
  __shared__ int moks[16];

  char* KsmB = (char*)Ksm;
  char* VsmB = (char*)Vsm;

  // ---- per-(m,tile) all-ones mask flags (once per block) ----
  if (tid < 16) moks[tid] = 1;
  __syncthreads();
  {
    int bad = 0;
    const int4* mg = (const int4*)&maskg[mI * T_SEQ + tid * 8];
    int4 a = mg[0], b = mg[1];
    bad |= (a.x == 0) | (a.y == 0) | (a.z == 0) | (a.w == 0);
    bad |= (b.x == 0) | (b.y == 0) | (b.z == 0) | (b.w == 0);
    if (bad) moks[tid >> 4] = 0;
  }
  __syncthreads();
  int okbits = 0;
#pragma unroll
  for (int i = 0; i < 16; ++i) okbits |= (moks[i] != 0) << i;

  // ---- Q fragments in registers (B-frag: col=q=lq, k=d) ----
  const int qrow = qt * 128 + w * 32 + lq;
  bf16x8 qf[4];
#pragma unroll
  for (int db = 0; db < 4; ++db)
    qf[db] = *(const bf16x8*)&qb[((size_t)(mI * T_SEQ) + qrow) * D_EMB + h * 64 + db * 16 + h2 * 8];

  f32x16 oacc[2] = {};
  float li = 0.f;

  const unsigned short* kpan = kb + (size_t)(mI * T_SEQ) * D_EMB + h * 64;
  const unsigned short* vpan = vtb + (size_t)(mI * H_HEADS + h) * 64 * T_SEQ;

#pragma unroll 1
  for (int t = sp * 8; t < sp * 8 + 8; ++t) {
    const int okv = (okbits >> t) & 1;
    const int k0s = t * 128;
    // ---- stage K [128][64] + Vt [64][128] (single buffer) ----
#pragma unroll
    for (int it = 0; it < 4; ++it) {
      int idx = it * 256 + tid;
      int row = idx >> 3;
      int sb = ((idx & 7) * 16) ^ ((row & 7) << 4);
      gl16(kpan + (size_t)(k0s + row) * D_EMB + (sb >> 1), KsmB + idx * 16);
    }
#pragma unroll
    for (int it = 0; it < 4; ++it) {
      int idx = it * 256 + tid;
      int row = idx >> 4;
      int sb = ((idx & 15) * 16) ^ ((row & 7) << 4);
      gl16(vpan + (size_t)row * T_SEQ + k0s + (sb >> 1), VsmB + idx * 16);
    }
    if (!okv && tid < 128)
      Msm[tid] = (maskg[mI * T_SEQ + k0s + tid] == 0) ? MASKNEG : 0.f;
    __syncthreads();

    // ---- 4 key-blocks of 32 ----
#pragma unroll 1
    for (int kbk = 0; kbk < 4; ++kbk) {
      f32x16 sv = {};
      const char* kr = KsmB + (kbk * 32 + lq) * 128;
#pragma unroll
      for (int db = 0; db < 4; ++db) {
        bf16x8 kf = *(const bf16x8*)(kr + ((db * 32 + h2 * 16) ^ xk));
        sv = __builtin_amdgcn_mfma_f32_32x32x16_bf16(kf, qf[db], sv, 0, 0, 0);
      }
      if (!okv) {
#pragma unroll
        for (int rg = 0; rg < 4; ++rg) {
          f32x4 mk = *(const f32x4*)&Msm[kbk * 32 + rg * 8 + h2 * 4];
          sv[rg * 4 + 0] += mk[0]; sv[rg * 4 + 1] += mk[1];
          sv[rg * 4 + 2] += mk[2]; sv[rg * 4 + 3] += mk[3];
        }
      }
#pragma unroll
      for (int r = 0; r < 16; ++r) sv[r] = fexp2(sv[r]);
      // scalar li via tree-sum
      {
        float t0 = (sv[0] + sv[1]) + (sv[2] + sv[3]);
        float t1 = (sv[4] + sv[5]) + (sv[6] + sv[7]);
        float t2 = (sv[8] + sv[9]) + (sv[10] + sv[11]);
        float t3 = (sv[12] + sv[13]) + (sv[14] + sv[15]);
        li += (t0 + t1) + (t2 + t3);
      }
      uint32_t w0 = cvtpk(sv[0], sv[1]), w1 = cvtpk(sv[2], sv[3]);
      uint32_t w2 = cvtpk(sv[4], sv[5]), w3 = cvtpk(sv[6], sv[7]);
      uint32_t w4 = cvtpk(sv[8], sv[9]), w5 = cvtpk(sv[10], sv[11]);
      uint32_t w6 = cvtpk(sv[12], sv[13]), w7 = cvtpk(sv[14], sv[15]);
      uint32_t x0 = __shfl_xor(w0, 32), x1 = __shfl_xor(w1, 32);
      uint32_t x2 = __shfl_xor(w2, 32), x3 = __shfl_xor(w3, 32);
      uint32_t x4 = __shfl_xor(w4, 32), x5 = __shfl_xor(w5, 32);
      uint32_t x6 = __shfl_xor(w6, 32), x7 = __shfl_xor(w7, 32);
      bf16x8 pf[2];
      {
        union { bf16x8 v; uint32_t u[4]; } u_;
        u_.u[0] = h2 ? x2 : w0; u_.u[1] = h2 ? x3 : w1;
        u_.u[2] = h2 ? w2 : x0; u_.u[3] = h2 ? w3 : x1;
        pf[0] = u_.v;
      }
      {
        union { bf16x8 v; uint32_t u[4]; } u_;
        u_.u[0] = h2 ? x6 : w4; u_.u[1] = h2 ? x7 : w5;
        u_.u[2] = h2 ? w6 : x4; u_.u[3] = h2 ? w7 : x5;
        pf[1] = u_.v;
      }
#pragma unroll
      for (int vb = 0; vb < 2; ++vb) {
        const char* vbase = VsmB + (vb * 32 + lq) * 256;
#pragma unroll
        for (int s = 0; s < 2; ++s) {
          bf16x8 vf = *(const bf16x8*)(vbase + ((kbk * 64 + s * 32 + h2 * 16) ^ vx));
          oacc[vb] = __builtin_amdgcn_mfma_f32_32x32x16_bf16(vf, pf[s], oacc[vb], 0, 0, 0);
        }
      }
    }
    __syncthreads();
  }

  // ---- epilogue: store PARTIAL oacc (bf16, undivided) + li (f32) ----
  li += __shfl_xor(li, 32);

  unsigned short* op = opart + (size_t)sp * ((size_t)MROWS * D_EMB);
  size_t orow = (size_t)(mI * T_SEQ + qrow) * D_EMB + h * 64;
#pragma unroll
  for (int vb = 0; vb < 2; ++vb)
#pragma unroll
    for (int rg = 0; rg < 4; ++rg) {
      uint2 ow;
      ow.x = cvtpk(oacc[vb][rg * 4 + 0], oacc[vb][rg * 4 + 1]);
      ow.y = cvtpk(oacc[vb][rg * 4 + 2], oacc[vb][rg * 4 + 3]);
      *(uint2*)&op[orow + vb * 32 + rg * 8 + h2 * 4] = ow;
    }
  if (h2 == 0)
    lipart[((size_t)sp * MROWS + mI * T_SEQ + qrow) * H_HEADS + h] = li;
}

// ---------------- combine: cc = (O0 + O1) / (li0 + li1), bf16 ----------------
__global__ __launch_bounds__(256) void combine(const unsigned short* __restrict__ opart,
                                               const float* __restrict__ lipart,
                                               unsigned short* __restrict__ cc) {
  int i = blockIdx.x * 256 + threadIdx.x;   // 524288 groups of 8
  int row = i >> 7;                          // 0..4095
  int c8 = i & 127;
  int h = c8 >> 3;
  float l0 = lipart[(size_t)row * H_HEADS + h];
  float l1 = lipart[((size_t)MROWS + row) * H_HEADS + h];
  float inv = 1.f / (l0 + l1);
  size_t off = (size_t)row * D_EMB + c8 * 8;
  us4 a0 = *(const us4*)&opart[off];
  us4 a1 = *(const us4*)&opart[off + 4];
  us4 b0 = *(const us4*)&opart[(size_t)MROWS * D_EMB + off];
  us4 b1 = *(const us4*)&opart[(size_t)MROWS * D_EMB + off + 4];
  uint2 o0, o1;
  o0.x = cvtpk((bf2f(a0[0]) + bf2f(b0[0])) * inv, (bf2f(a0[1]) + bf2f(b0[1])) * inv);
  o0.y = cvtpk((bf2f(a0[2]) + bf2f(b0[2])) * inv, (bf2f(a0[3]) + bf2f(b0[3])) * inv);
  o1.x = cvtpk((bf2f(a1[0]) + bf2f(b1[0])) * inv, (bf2f(a1[1]) + bf2f(b1[1])) * inv);
  o1.y = cvtpk((bf2f(a1[2]) + bf2f(b1[2])) * inv, (bf2f(a1[3]) + bf2f(b1[3])) * inv);
  *(uint2*)&cc[off] = o0;
  *(uint2*)&cc[off + 4] = o1;
}

extern "C" void kernel_launch(void* const* d_in, const int* in_sizes, int n_in,
                              void* d_out, int out_size, void* d_ws, size_t ws_size,
                              hipStream_t stream) {
  const float* Q  = (const float*)d_in[0];
  const float* K  = (const float*)d_in[1];
  const float* V  = (const float*)d_in[2];
  const int* mask = (const int*)d_in[3];
  const float* Wq = (const float*)d_in[4];
  const float* bq = (const float*)d_in[5];
  const float* Wk = (const float*)d_in[6];
  const float* bk = (const float*)d_in[7];
  const float* Wv = (const float*)d_in[8];
  const float* bv = (const float*)d_in[9];
  const float* Wo = (const float*)d_in[10];
  const float* bo = (const float*)d_in[11];

  uint8_t* ws = (uint8_t*)d_ws;
  const size_t MB = 1u << 20;
  unsigned short* Wq_b = (unsigned short*)(ws + 0 * MB);
  unsigned short* Wk_b = (unsigned short*)(ws + 2 * MB);
  unsigned short* Wv_b = (unsigned short*)(ws + 4 * MB);
  unsigned short* Wo_b = (unsigned short*)(ws + 6 * MB);
  unsigned short* q_b  = (unsigned short*)(ws + 8 * MB);
  unsigned short* k_b  = (unsigned short*)(ws + 16 * MB);
  unsigned short* vt_b = (unsigned short*)(ws + 24 * MB);
  // Qb/Kb/Vb (bf16 GEMM inputs) at 32/40/48 MB are dead after qkv_gemm:
  // opart (2x8MB) aliases Qb+Kb; cc_b aliases Vb; lipart fresh at 56 MB.
  unsigned short* Qb    = (unsigned short*)(ws + 32 * MB);
  unsigned short* Kb    = (unsigned short*)(ws + 40 * MB);
  unsigned short* Vb    = (unsigned short*)(ws + 48 * MB);
  unsigned short* opart = (unsigned short*)(ws + 32 * MB);
  unsigned short* cc_b  = (unsigned short*)(ws + 48 * MB);
  float*          lipart = (float*)(ws + 56 * MB);

  cvt_all<<<dim3(16384), dim3(256), 0, stream>>>(Q, K, V, Wq, Wk, Wv, Wo,
                                                 Qb, Kb, Vb, Wq_b, Wk_b, Wv_b, Wo_b);

  qkv_gemm<<<dim3(1536), dim3(256), 0, stream>>>(
      Qb, Kb, Vb, Wq_b, Wk_b, Wv_b, bq, bk, bv, q_b, k_b, vt_b);

  attn_fwd<<<dim3(1024), dim3(256), 0, stream>>>(
      q_b, k_b, vt_b, mask, opart, lipart);

  combine<<<dim3(2048), dim3(256), 0, stream>>>(opart, lipart, cc_b);

  out_gemm<<<dim3(512), dim3(256), 0, stream>>>(
      cc_b, Wo_b, bo, (float*)d_out);
}